// Round 13
// baseline (243.157 us; speedup 1.0000x reference)
//
#include <hip/hip_runtime.h>
#include <math.h>

#define N_NODES 512
#define DIM 128
#define NANCH 192
#define G3 384           // 3*DIM gate width
#define FOUT 47
#define DBINS 21

__device__ __forceinline__ float fast_sigmoid(float x) {
    return __builtin_amdgcn_rcpf(1.f + __expf(-x));
}
__device__ __forceinline__ float fast_tanh(float x) {
    return 1.f - 2.f * __builtin_amdgcn_rcpf(1.f + __expf(2.f * x));
}

// ============ Kernel 1: fused [xW GEMM | membership + abnormal + H=1 BiGRU] ============
// blocks 0..191   : xW = x @ Wih^T + bih  (sd = blk>>5, node-group = blk&31)
// blocks 192..383 : per-anchor membership list + abnormal scores + scalar BiGRU
__global__ __launch_bounds__(384) void prep_kernel(
    const float* __restrict__ emb, const float* __restrict__ tpin,
    const float* __restrict__ Wih, const float* __restrict__ bih,
    const float* __restrict__ alp, const float* __restrict__ anchors,
    const float* __restrict__ npred, const float* __restrict__ skern,
    const float* __restrict__ aWih, const float* __restrict__ aWhh,
    const float* __restrict__ abih, const float* __restrict__ abhh,
    float* __restrict__ xW, int* __restrict__ members,
    int* __restrict__ lens, float* __restrict__ abn_res)
{
    int blk = blockIdx.x;
    int tid = threadIdx.x;     // 0..383
    if (blk < 192) {
        int sd = blk >> 5;         // 0..5
        int ng = blk & 31;         // 0..31
        __shared__ __align__(16) float xs[16][DIM];
        for (int idx = tid; idx < 16 * DIM; idx += 384) {
            int m = idx >> 7, k = idx & 127;
            int node = ng * 16 + m;
            float tv = tpin[node];
            float freq = 10.f * (float)k / 127.f;
            xs[m][k] = emb[node * DIM + k] + 0.05f * __sinf(tv * freq);
        }
        __syncthreads();
        float acc[16];
        float b = bih[sd * G3 + tid];
        #pragma unroll
        for (int m = 0; m < 16; ++m) acc[m] = b;
        const float* wrow = Wih + ((size_t)sd * G3 + tid) * DIM;
        for (int k = 0; k < DIM; k += 4) {
            float4 w4 = *(const float4*)(wrow + k);
            #pragma unroll
            for (int m = 0; m < 16; ++m) {
                float4 xv = *(const float4*)&xs[m][k];   // wave-uniform b128 broadcast
                acc[m] = fmaf(w4.x, xv.x, acc[m]);
                acc[m] = fmaf(w4.y, xv.y, acc[m]);
                acc[m] = fmaf(w4.z, xv.z, acc[m]);
                acc[m] = fmaf(w4.w, xv.w, acc[m]);
            }
        }
        #pragma unroll
        for (int m = 0; m < 16; ++m)
            xW[((size_t)sd * N_NODES + ng * 16 + m) * G3 + tid] = acc[m];
    } else {
        int a = blk - 192;
        float al = alp[0];
        float s0 = anchors[a * 2 + 0];
        float e0 = anchors[a * 2 + 1];
        __shared__ int memloc[N_NODES];
        __shared__ float abn_lds[N_NODES];
        for (int node = tid; node < N_NODES; node += 384) {
            float sc[5];
            #pragma unroll
            for (int ch = 0; ch < 5; ++ch) {
                float acc = 0.f;
                #pragma unroll
                for (int k = 0; k < 5; ++k) {
                    int r = node + k - 2;
                    if (r >= 0 && r < N_NODES) acc += skern[k] * npred[r * 5 + ch];
                }
                sc[ch] = acc;
            }
            float m = sc[0];
            #pragma unroll
            for (int ch = 1; ch < 5; ++ch) m = fmaxf(m, sc[ch]);
            float sum = 0.f;
            #pragma unroll
            for (int ch = 0; ch < 5; ++ch) sum += __expf(sc[ch] - m);
            abn_lds[node] = __expf(sc[0] - m) / sum;
        }
        __syncthreads();
        if (tid < 64) {
            int lane = tid;
            int count = 0;
            for (int c = 0; c < N_NODES / 64; ++c) {
                int node = c * 64 + lane;
                float tp = tpin[node] * al;
                bool in = (tp >= s0) && (tp <= e0);
                unsigned long long m = __ballot(in);
                if (in) {
                    int pos = count + __popcll(m & ((1ull << lane) - 1ull));
                    members[a * N_NODES + pos] = node;
                    memloc[pos] = node;
                }
                count += __popcll(m);
            }
            if (lane == 0) lens[a] = count;
            int sc3 = a >> 6;
            float h = 0.f;
            if (lane < 2) {
                int sd = sc3 * 2 + lane;
                float wi0 = aWih[sd*3+0], wi1 = aWih[sd*3+1], wi2 = aWih[sd*3+2];
                float wh0 = aWhh[sd*3+0], wh1 = aWhh[sd*3+1], wh2 = aWhh[sd*3+2];
                float bi0 = abih[sd*3+0], bi1 = abih[sd*3+1], bi2 = abih[sd*3+2];
                float bh0 = abhh[sd*3+0], bh1 = abhh[sd*3+1], bh2 = abhh[sd*3+2];
                for (int t = 0; t < count; ++t) {
                    int idx = lane ? (count - 1 - t) : t;
                    float xv = abn_lds[memloc[idx]];
                    float r = fast_sigmoid(fmaf(wi0, xv, bi0) + fmaf(wh0, h, bh0));
                    float z = fast_sigmoid(fmaf(wi1, xv, bi1) + fmaf(wh1, h, bh1));
                    float nv = fast_tanh(fmaf(wi2, xv, bi2) + r * fmaf(wh2, h, bh2));
                    h = (1.f - z) * nv + z * h;
                }
            }
            float hb = __shfl(h, 1);
            if (lane == 0) abn_res[a] = 0.5f * (h + hb);
        }
    }
}

// ============ Kernel 2: H=128 GRU — R12 (sorted placement) + n-gate weights in LDS ============
// R12 established: makespan = longest anchor x SOLO per-step rate (2250 cyc), which is
// L1-BW-bound on the 196 KB/step Whh remat stream (+~700 cyc fixed). LDS and vector-mem
// are parallel pipes: stage the n-gate (64 KB) into LDS once ([q][tid] layout -> lane
// stride 16B, LDS data-movement floor), keep r/z gates on the L1 remat path. Solo L1
// traffic drops 196->131 KB/step; LDS adds ~500 cyc on the other pipe.
// 2 blocks/CU preserved: LDS/block ~67.5 KB (2x = 135 <= 160 KB). Inner loop otherwise
// identical to R8/R12 (VGPR-64 live set, hj re-read from LDS, no pins).
__global__ __launch_bounds__(512, 2) void gru_feat_kernel(
    const float* __restrict__ xW, const float* __restrict__ Whh,
    const float* __restrict__ bhh, const int* __restrict__ members,
    const int* __restrict__ lens, const float* __restrict__ anchors,
    float* __restrict__ feat_out)
{
    int b = blockIdx.x;
    int t0 = threadIdx.x;      // 0..511
    int j  = t0 >> 2;          // 0..127 : owned h element
    int s  = t0 & 3;           // 0..3   : 32-wide K slice

    // ---- rank anchors by width desc (bijective; ties broken by index) ----
    __shared__ int perm_l[NANCH];
    if (t0 < NANCH) {
        float w = anchors[2 * t0 + 1] - anchors[2 * t0];
        int rank = 0;
        for (int q = 0; q < NANCH; ++q) {
            float wq = anchors[2 * q + 1] - anchors[2 * q];
            rank += (wq > w) || (wq == w && q < t0);
        }
        perm_l[rank] = t0;
    }
    __syncthreads();
    int k, dir;
    if (b >= 128 && b < 256) { int i = b - 128; k = i >> 1;        dir = i & 1; } // ranks 0..63  (solo CUs)
    else if (b < 128)        {                  k = 64 + (b >> 1); dir = b & 1; } // ranks 64..127 (shared)
    else                     { int i = b - 256; k = 128 + (i >> 1); dir = i & 1; } // ranks 128..191 (shared)
    int a  = perm_l[k];
    int s3 = a >> 6;           // scale
    int sd = s3 * 2 + dir;

    // ---- stage n-gate weights into LDS ([q][tid]: lane-contiguous float4 reads) ----
    __shared__ __align__(16) float4 wn_lds[8][512];
    // preload r/z gates into registers (compiler remats these loads from L1 — the
    // measured-optimal path for the streamed portion)
    float wr[32], wz[32];
    {
        const float* base = Whh + ((size_t)sd * G3) * DIM;
        const float* pr = base + (size_t)(j        ) * DIM + s * 32;
        const float* pz = base + (size_t)(j + DIM  ) * DIM + s * 32;
        const float* pn = base + (size_t)(j + 2*DIM) * DIM + s * 32;
        #pragma unroll
        for (int q = 0; q < 8; ++q) {
            float4 v = *(const float4*)(pr + 4 * q);
            wr[4*q+0]=v.x; wr[4*q+1]=v.y; wr[4*q+2]=v.z; wr[4*q+3]=v.w;
        }
        #pragma unroll
        for (int q = 0; q < 8; ++q) {
            float4 v = *(const float4*)(pz + 4 * q);
            wz[4*q+0]=v.x; wz[4*q+1]=v.y; wz[4*q+2]=v.z; wz[4*q+3]=v.w;
        }
        #pragma unroll
        for (int q = 0; q < 8; ++q)
            wn_lds[q][t0] = *(const float4*)(pn + 4 * q);
    }
    float bhr = bhh[sd * G3 + j];
    float bhz = bhh[sd * G3 + DIM + j];
    float bhn = bhh[sd * G3 + 2 * DIM + j];

    const float* xWp = xW + (size_t)sd * N_NODES * G3;
    const int* mem = members + a * N_NODES;
    int len = lens[a];

    // h ping-pong, slice-padded: slice s at [buf][s][0..31], stride 36 floats
    __shared__ __align__(16) float hbuf[2][4][36];
    for (int i = t0; i < 2 * 4 * 36; i += 512) ((float*)hbuf)[i] = 0.f;
    __syncthreads();

    // prefetch gi for step 0
    int node0 = (len > 0) ? mem[dir ? (len - 1) : 0] : 0;
    float gr = xWp[(size_t)node0 * G3 + j];
    float gz = xWp[(size_t)node0 * G3 + DIM + j];
    float gn = xWp[(size_t)node0 * G3 + 2 * DIM + j];

    int cur = 0;
    for (int t = 0; t < len; ++t) {
        // prefetch next step's gi (overlaps this step's compute + barrier)
        float gr_n = 0.f, gz_n = 0.f, gn_n = 0.f;
        if (t + 1 < len) {
            int nn = mem[dir ? (len - 2 - t) : (t + 1)];
            gr_n = xWp[(size_t)nn * G3 + j];
            gz_n = xWp[(size_t)nn * G3 + DIM + j];
            gn_n = xWp[(size_t)nn * G3 + 2 * DIM + j];
        }
        // partial dots over this thread's 32-wide K slice
        float ar = 0.f, az = 0.f, an_ = 0.f;
        const float4* hp = (const float4*)(&hbuf[cur][s][0]);
        #pragma unroll
        for (int q = 0; q < 8; ++q) {
            float4 hv = hp[q];
            float4 wv = wn_lds[q][t0];          // LDS pipe (parallel to L1 remat stream)
            ar = fmaf(wr[4*q+0], hv.x, ar); ar = fmaf(wr[4*q+1], hv.y, ar);
            ar = fmaf(wr[4*q+2], hv.z, ar); ar = fmaf(wr[4*q+3], hv.w, ar);
            az = fmaf(wz[4*q+0], hv.x, az); az = fmaf(wz[4*q+1], hv.y, az);
            az = fmaf(wz[4*q+2], hv.z, az); az = fmaf(wz[4*q+3], hv.w, az);
            an_ = fmaf(wv.x, hv.x, an_); an_ = fmaf(wv.y, hv.y, an_);
            an_ = fmaf(wv.z, hv.z, an_); an_ = fmaf(wv.w, hv.w, an_);
        }
        // quad reduction (lanes 4j..4j+3 adjacent in wave)
        ar  += __shfl_xor(ar, 1);  ar  += __shfl_xor(ar, 2);
        az  += __shfl_xor(az, 1);  az  += __shfl_xor(az, 2);
        an_ += __shfl_xor(an_, 1); an_ += __shfl_xor(an_, 2);

        float r  = fast_sigmoid(gr + ar + bhr);
        float z  = fast_sigmoid(gz + az + bhz);
        float nv = fast_tanh(gn + r * (an_ + bhn));
        float hj = hbuf[cur][j >> 5][j & 31];     // LDS re-read: keeps live set at 64 VGPR
        float hnew = (1.f - z) * nv + z * hj;
        if (s == 0) hbuf[cur ^ 1][j >> 5][j & 31] = hnew;
        __syncthreads();
        cur ^= 1;
        gr = gr_n; gz = gz_n; gn = gn_n;
    }
    if (s == 0) feat_out[a * 256 + dir * DIM + j] = hbuf[cur][j >> 5][j & 31];
}

// ============ Kernel 3: per-anchor MLP head + boundary refinement ============
__global__ __launch_bounds__(256) void head_kernel(
    const float* __restrict__ feat, const float* __restrict__ abn_res,
    const float* __restrict__ anchors, const float* __restrict__ alp,
    const float* __restrict__ W1, const float* __restrict__ b1,
    const float* __restrict__ W2, const float* __restrict__ b2,
    const float* __restrict__ W3, const float* __restrict__ b3,
    const float* __restrict__ sw, const float* __restrict__ ew,
    float* __restrict__ out)
{
    int a = blockIdx.x;
    int tid = threadIdx.x;   // 0..255
    int s = a >> 6;
    __shared__ float sf[260];
    __shared__ float h1[256];
    __shared__ float h2[256];
    __shared__ float o[FOUT];
    float al = alp[0];
    float st = anchors[a * 2 + 0];
    float en = anchors[a * 2 + 1];
    sf[tid] = feat[a * 256 + tid];
    if (tid == 0) {
        sf[256] = abn_res[a];
        sf[257] = (st + en) * 0.5f / al;
        sf[258] = (en - st) / al;
    }
    __syncthreads();

    const float* w1 = W1 + (size_t)s * 259 * 256;
    float acc = b1[s * 256 + tid];
    for (int jj = 0; jj < 259; ++jj) acc = fmaf(sf[jj], w1[jj * 256 + tid], acc);
    h1[tid] = fmaxf(acc, 0.f);
    __syncthreads();

    const float* w2 = W2 + (size_t)s * 256 * 256;
    acc = b2[s * 256 + tid];
    for (int jj = 0; jj < 256; ++jj) acc = fmaf(h1[jj], w2[jj * 256 + tid], acc);
    h2[tid] = fmaxf(acc, 0.f);
    __syncthreads();

    if (tid < FOUT) {
        const float* w3 = W3 + (size_t)s * 256 * FOUT;
        acc = b3[s * FOUT + tid];
        for (int jj = 0; jj < 256; ++jj) acc = fmaf(h2[jj], w3[jj * FOUT + tid], acc);
        o[tid] = acc;
    }
    __syncthreads();

    if (tid < 2) {   // tid 0: start offset, tid 1: end offset
        const float* lw = (tid == 0) ? (sw + s * DBINS) : (ew + s * DBINS);
        const float* sl = o + tid * DBINS;
        float m = sl[0];
        for (int jj = 1; jj < DBINS; ++jj) m = fmaxf(m, sl[jj]);
        float sum = 0.f, dot = 0.f;
        for (int jj = 0; jj < DBINS; ++jj) {
            float e = __expf(sl[jj] - m);
            sum += e;
            dot = fmaf(e, lw[jj], dot);
        }
        float off = dot / sum;
        float base = (tid == 0) ? st : en;
        out[a * 2 + tid] = fminf(fmaxf(base + off, 0.f), al);
    }
    if (tid == 42) out[2 * NANCH + a] = o[42];                           // conf
    if (tid >= 43 && tid < FOUT) out[3 * NANCH + a * 4 + (tid - 43)] = o[tid]; // cls
}

extern "C" void kernel_launch(void* const* d_in, const int* in_sizes, int n_in,
                              void* d_out, int out_size, void* d_ws, size_t ws_size,
                              hipStream_t stream) {
    const float* emb   = (const float*)d_in[0];
    const float* tpin  = (const float*)d_in[1];
    const float* npred = (const float*)d_in[2];
    const float* alp   = (const float*)d_in[3];
    const float* anch  = (const float*)d_in[4];
    const float* skern = (const float*)d_in[5];
    const float* fWih  = (const float*)d_in[6];
    const float* fWhh  = (const float*)d_in[7];
    const float* fbih  = (const float*)d_in[8];
    const float* fbhh  = (const float*)d_in[9];
    const float* aWih  = (const float*)d_in[10];
    const float* aWhh  = (const float*)d_in[11];
    const float* abih  = (const float*)d_in[12];
    const float* abhh  = (const float*)d_in[13];
    const float* sw    = (const float*)d_in[14];
    const float* ew    = (const float*)d_in[15];
    const float* W1    = (const float*)d_in[16];
    const float* b1    = (const float*)d_in[17];
    const float* W2    = (const float*)d_in[18];
    const float* b2    = (const float*)d_in[19];
    const float* W3    = (const float*)d_in[20];
    const float* b3    = (const float*)d_in[21];

    float* ws = (float*)d_ws;
    float* xW       = ws;                      // 6*512*384 = 1179648
    float* abn_res  = ws + 1179648;            // 192 (pad 256)
    float* feat     = ws + 1179904;            // 192*256 = 49152
    int*   members  = (int*)(ws + 1229056);    // 192*512 ints = 98304
    int*   lens     = (int*)(ws + 1327360);    // 192 ints
    float* outp     = (float*)d_out;

    prep_kernel<<<384, 384, 0, stream>>>(emb, tpin, fWih, fbih, alp, anch, npred, skern,
                                         aWih, aWhh, abih, abhh,
                                         xW, members, lens, abn_res);
    gru_feat_kernel<<<2 * NANCH, 512, 0, stream>>>(xW, fWhh, fbhh, members, lens, anch, feat);
    head_kernel<<<NANCH, 256, 0, stream>>>(feat, abn_res, anch, alp,
                                           W1, b1, W2, b2, W3, b3, sw, ew, outp);
}

// Round 14
// 238.367 us; speedup vs baseline: 1.0201x; 1.0201x over previous
//
#include <hip/hip_runtime.h>
#include <math.h>

#define N_NODES 512
#define DIM 128
#define NANCH 192
#define G3 384           // 3*DIM gate width
#define FOUT 47
#define DBINS 21

__device__ __forceinline__ float fast_sigmoid(float x) {
    return __builtin_amdgcn_rcpf(1.f + __expf(-x));
}
__device__ __forceinline__ float fast_tanh(float x) {
    return 1.f - 2.f * __builtin_amdgcn_rcpf(1.f + __expf(2.f * x));
}

// ============ Kernel 1: fused [xW GEMM | membership + abnormal + H=1 BiGRU] ============
// blocks 0..191   : xW = x @ Wih^T + bih  (sd = blk>>5, node-group = blk&31)
// blocks 192..383 : per-anchor membership list + abnormal scores + scalar BiGRU
__global__ __launch_bounds__(384) void prep_kernel(
    const float* __restrict__ emb, const float* __restrict__ tpin,
    const float* __restrict__ Wih, const float* __restrict__ bih,
    const float* __restrict__ alp, const float* __restrict__ anchors,
    const float* __restrict__ npred, const float* __restrict__ skern,
    const float* __restrict__ aWih, const float* __restrict__ aWhh,
    const float* __restrict__ abih, const float* __restrict__ abhh,
    float* __restrict__ xW, int* __restrict__ members,
    int* __restrict__ lens, float* __restrict__ abn_res)
{
    int blk = blockIdx.x;
    int tid = threadIdx.x;     // 0..383
    if (blk < 192) {
        int sd = blk >> 5;         // 0..5
        int ng = blk & 31;         // 0..31
        __shared__ __align__(16) float xs[16][DIM];
        for (int idx = tid; idx < 16 * DIM; idx += 384) {
            int m = idx >> 7, k = idx & 127;
            int node = ng * 16 + m;
            float tv = tpin[node];
            float freq = 10.f * (float)k / 127.f;
            xs[m][k] = emb[node * DIM + k] + 0.05f * __sinf(tv * freq);
        }
        __syncthreads();
        float acc[16];
        float b = bih[sd * G3 + tid];
        #pragma unroll
        for (int m = 0; m < 16; ++m) acc[m] = b;
        const float* wrow = Wih + ((size_t)sd * G3 + tid) * DIM;
        for (int k = 0; k < DIM; k += 4) {
            float4 w4 = *(const float4*)(wrow + k);
            #pragma unroll
            for (int m = 0; m < 16; ++m) {
                float4 xv = *(const float4*)&xs[m][k];   // wave-uniform b128 broadcast
                acc[m] = fmaf(w4.x, xv.x, acc[m]);
                acc[m] = fmaf(w4.y, xv.y, acc[m]);
                acc[m] = fmaf(w4.z, xv.z, acc[m]);
                acc[m] = fmaf(w4.w, xv.w, acc[m]);
            }
        }
        #pragma unroll
        for (int m = 0; m < 16; ++m)
            xW[((size_t)sd * N_NODES + ng * 16 + m) * G3 + tid] = acc[m];
    } else {
        int a = blk - 192;
        float al = alp[0];
        float s0 = anchors[a * 2 + 0];
        float e0 = anchors[a * 2 + 1];
        __shared__ int memloc[N_NODES];
        __shared__ float abn_lds[N_NODES];
        for (int node = tid; node < N_NODES; node += 384) {
            float sc[5];
            #pragma unroll
            for (int ch = 0; ch < 5; ++ch) {
                float acc = 0.f;
                #pragma unroll
                for (int k = 0; k < 5; ++k) {
                    int r = node + k - 2;
                    if (r >= 0 && r < N_NODES) acc += skern[k] * npred[r * 5 + ch];
                }
                sc[ch] = acc;
            }
            float m = sc[0];
            #pragma unroll
            for (int ch = 1; ch < 5; ++ch) m = fmaxf(m, sc[ch]);
            float sum = 0.f;
            #pragma unroll
            for (int ch = 0; ch < 5; ++ch) sum += __expf(sc[ch] - m);
            abn_lds[node] = __expf(sc[0] - m) / sum;
        }
        __syncthreads();
        if (tid < 64) {
            int lane = tid;
            int count = 0;
            for (int c = 0; c < N_NODES / 64; ++c) {
                int node = c * 64 + lane;
                float tp = tpin[node] * al;
                bool in = (tp >= s0) && (tp <= e0);
                unsigned long long m = __ballot(in);
                if (in) {
                    int pos = count + __popcll(m & ((1ull << lane) - 1ull));
                    members[a * N_NODES + pos] = node;
                    memloc[pos] = node;
                }
                count += __popcll(m);
            }
            if (lane == 0) lens[a] = count;
            int sc3 = a >> 6;
            float h = 0.f;
            if (lane < 2) {
                int sd = sc3 * 2 + lane;
                float wi0 = aWih[sd*3+0], wi1 = aWih[sd*3+1], wi2 = aWih[sd*3+2];
                float wh0 = aWhh[sd*3+0], wh1 = aWhh[sd*3+1], wh2 = aWhh[sd*3+2];
                float bi0 = abih[sd*3+0], bi1 = abih[sd*3+1], bi2 = abih[sd*3+2];
                float bh0 = abhh[sd*3+0], bh1 = abhh[sd*3+1], bh2 = abhh[sd*3+2];
                for (int t = 0; t < count; ++t) {
                    int idx = lane ? (count - 1 - t) : t;
                    float xv = abn_lds[memloc[idx]];
                    float r = fast_sigmoid(fmaf(wi0, xv, bi0) + fmaf(wh0, h, bh0));
                    float z = fast_sigmoid(fmaf(wi1, xv, bi1) + fmaf(wh1, h, bh1));
                    float nv = fast_tanh(fmaf(wi2, xv, bi2) + r * fmaf(wh2, h, bh2));
                    h = (1.f - z) * nv + z * h;
                }
            }
            float hb = __shfl(h, 1);
            if (lane == 0) abn_res[a] = 0.5f * (h + hb);
        }
    }
}

// ============ Kernel 2: H=128 GRU recurrence — R12 FINAL (95.5 us, VGPR 64) ============
// Converged configuration. Invariants, each established by a measured regression:
//  - R8 inner loop byte-identical: hj RE-READ from LDS (live set = 64 VGPR exactly;
//    65+ halves wave capacity — R7: +4 VGPR = +20 us).
//  - No pins / waves_per_eu / fences / appended phases (R3/R5/R6/R10 regressed;
//    __threadfence in-kernel poisons the co-resident block's L1 — R10).
//  - 384 blocks, 2/CU on shared CUs: cross-block TLP hides the weight-remat chain
//    (R9's 1-block/CU: -TLP = +33 us). Weight traffic is NOT the binding constraint
//    (R13: moving 1/3 to LDS regressed; solo draws 87 B/cyc vs 157 B/cyc demonstrated
//    capacity) — the solo step is latency-bound on barrier->ds_read->fma->shfl chain.
//  - Width-sorted placement: HW maps blocks (b, b+256) to one CU; IDs 128..255 run
//    solo. The 64 widest anchors get the solo IDs -> makespan = longest anchor at the
//    solo rate (R12: -11 us).
__global__ __launch_bounds__(512, 2) void gru_feat_kernel(
    const float* __restrict__ xW, const float* __restrict__ Whh,
    const float* __restrict__ bhh, const int* __restrict__ members,
    const int* __restrict__ lens, const float* __restrict__ anchors,
    float* __restrict__ feat_out)
{
    int b = blockIdx.x;
    int t0 = threadIdx.x;      // 0..511
    int j  = t0 >> 2;          // 0..127 : owned h element
    int s  = t0 & 3;           // 0..3   : 32-wide K slice

    // ---- rank anchors by width desc (bijective; ties broken by index) ----
    __shared__ int perm_l[NANCH];
    if (t0 < NANCH) {
        float w = anchors[2 * t0 + 1] - anchors[2 * t0];
        int rank = 0;
        for (int q = 0; q < NANCH; ++q) {
            float wq = anchors[2 * q + 1] - anchors[2 * q];
            rank += (wq > w) || (wq == w && q < t0);
        }
        perm_l[rank] = t0;
    }
    __syncthreads();
    int k, dir;
    if (b >= 128 && b < 256) { int i = b - 128; k = i >> 1;        dir = i & 1; } // ranks 0..63  (solo CUs)
    else if (b < 128)        {                  k = 64 + (b >> 1); dir = b & 1; } // ranks 64..127 (shared)
    else                     { int i = b - 256; k = 128 + (i >> 1); dir = i & 1; } // ranks 128..191 (shared)
    int a  = perm_l[k];
    int s3 = a >> 6;           // scale
    int sd = s3 * 2 + dir;

    // preload this thread's Whh slices (compiler remats these loads; that's the measured optimum)
    float wr[32], wz[32], wn[32];
    {
        const float* base = Whh + ((size_t)sd * G3) * DIM;
        const float* pr = base + (size_t)(j        ) * DIM + s * 32;
        const float* pz = base + (size_t)(j + DIM  ) * DIM + s * 32;
        const float* pn = base + (size_t)(j + 2*DIM) * DIM + s * 32;
        #pragma unroll
        for (int q = 0; q < 8; ++q) {
            float4 v = *(const float4*)(pr + 4 * q);
            wr[4*q+0]=v.x; wr[4*q+1]=v.y; wr[4*q+2]=v.z; wr[4*q+3]=v.w;
        }
        #pragma unroll
        for (int q = 0; q < 8; ++q) {
            float4 v = *(const float4*)(pz + 4 * q);
            wz[4*q+0]=v.x; wz[4*q+1]=v.y; wz[4*q+2]=v.z; wz[4*q+3]=v.w;
        }
        #pragma unroll
        for (int q = 0; q < 8; ++q) {
            float4 v = *(const float4*)(pn + 4 * q);
            wn[4*q+0]=v.x; wn[4*q+1]=v.y; wn[4*q+2]=v.z; wn[4*q+3]=v.w;
        }
    }
    float bhr = bhh[sd * G3 + j];
    float bhz = bhh[sd * G3 + DIM + j];
    float bhn = bhh[sd * G3 + 2 * DIM + j];

    const float* xWp = xW + (size_t)sd * N_NODES * G3;
    const int* mem = members + a * N_NODES;
    int len = lens[a];

    // h ping-pong, slice-padded: slice s at [buf][s][0..31], stride 36 floats
    __shared__ __align__(16) float hbuf[2][4][36];
    for (int i = t0; i < 2 * 4 * 36; i += 512) ((float*)hbuf)[i] = 0.f;
    __syncthreads();

    // prefetch gi for step 0
    int node0 = (len > 0) ? mem[dir ? (len - 1) : 0] : 0;
    float gr = xWp[(size_t)node0 * G3 + j];
    float gz = xWp[(size_t)node0 * G3 + DIM + j];
    float gn = xWp[(size_t)node0 * G3 + 2 * DIM + j];

    int cur = 0;
    for (int t = 0; t < len; ++t) {
        // prefetch next step's gi (overlaps this step's compute + barrier)
        float gr_n = 0.f, gz_n = 0.f, gn_n = 0.f;
        if (t + 1 < len) {
            int nn = mem[dir ? (len - 2 - t) : (t + 1)];
            gr_n = xWp[(size_t)nn * G3 + j];
            gz_n = xWp[(size_t)nn * G3 + DIM + j];
            gn_n = xWp[(size_t)nn * G3 + 2 * DIM + j];
        }
        // partial dots over this thread's 32-wide K slice
        float ar = 0.f, az = 0.f, an_ = 0.f;
        const float4* hp = (const float4*)(&hbuf[cur][s][0]);
        #pragma unroll
        for (int q = 0; q < 8; ++q) {
            float4 hv = hp[q];
            ar = fmaf(wr[4*q+0], hv.x, ar); ar = fmaf(wr[4*q+1], hv.y, ar);
            ar = fmaf(wr[4*q+2], hv.z, ar); ar = fmaf(wr[4*q+3], hv.w, ar);
            az = fmaf(wz[4*q+0], hv.x, az); az = fmaf(wz[4*q+1], hv.y, az);
            az = fmaf(wz[4*q+2], hv.z, az); az = fmaf(wz[4*q+3], hv.w, az);
            an_ = fmaf(wn[4*q+0], hv.x, an_); an_ = fmaf(wn[4*q+1], hv.y, an_);
            an_ = fmaf(wn[4*q+2], hv.z, an_); an_ = fmaf(wn[4*q+3], hv.w, an_);
        }
        // quad reduction (lanes 4j..4j+3 adjacent in wave)
        ar  += __shfl_xor(ar, 1);  ar  += __shfl_xor(ar, 2);
        az  += __shfl_xor(az, 1);  az  += __shfl_xor(az, 2);
        an_ += __shfl_xor(an_, 1); an_ += __shfl_xor(an_, 2);

        float r  = fast_sigmoid(gr + ar + bhr);
        float z  = fast_sigmoid(gz + az + bhz);
        float nv = fast_tanh(gn + r * (an_ + bhn));
        float hj = hbuf[cur][j >> 5][j & 31];     // LDS re-read: keeps live set at 64 VGPR
        float hnew = (1.f - z) * nv + z * hj;
        if (s == 0) hbuf[cur ^ 1][j >> 5][j & 31] = hnew;
        __syncthreads();
        cur ^= 1;
        gr = gr_n; gz = gz_n; gn = gn_n;
    }
    if (s == 0) feat_out[a * 256 + dir * DIM + j] = hbuf[cur][j >> 5][j & 31];
}

// ============ Kernel 3: per-anchor MLP head + boundary refinement ============
__global__ __launch_bounds__(256) void head_kernel(
    const float* __restrict__ feat, const float* __restrict__ abn_res,
    const float* __restrict__ anchors, const float* __restrict__ alp,
    const float* __restrict__ W1, const float* __restrict__ b1,
    const float* __restrict__ W2, const float* __restrict__ b2,
    const float* __restrict__ W3, const float* __restrict__ b3,
    const float* __restrict__ sw, const float* __restrict__ ew,
    float* __restrict__ out)
{
    int a = blockIdx.x;
    int tid = threadIdx.x;   // 0..255
    int s = a >> 6;
    __shared__ float sf[260];
    __shared__ float h1[256];
    __shared__ float h2[256];
    __shared__ float o[FOUT];
    float al = alp[0];
    float st = anchors[a * 2 + 0];
    float en = anchors[a * 2 + 1];
    sf[tid] = feat[a * 256 + tid];
    if (tid == 0) {
        sf[256] = abn_res[a];
        sf[257] = (st + en) * 0.5f / al;
        sf[258] = (en - st) / al;
    }
    __syncthreads();

    const float* w1 = W1 + (size_t)s * 259 * 256;
    float acc = b1[s * 256 + tid];
    for (int jj = 0; jj < 259; ++jj) acc = fmaf(sf[jj], w1[jj * 256 + tid], acc);
    h1[tid] = fmaxf(acc, 0.f);
    __syncthreads();

    const float* w2 = W2 + (size_t)s * 256 * 256;
    acc = b2[s * 256 + tid];
    for (int jj = 0; jj < 256; ++jj) acc = fmaf(h1[jj], w2[jj * 256 + tid], acc);
    h2[tid] = fmaxf(acc, 0.f);
    __syncthreads();

    if (tid < FOUT) {
        const float* w3 = W3 + (size_t)s * 256 * FOUT;
        acc = b3[s * FOUT + tid];
        for (int jj = 0; jj < 256; ++jj) acc = fmaf(h2[jj], w3[jj * FOUT + tid], acc);
        o[tid] = acc;
    }
    __syncthreads();

    if (tid < 2) {   // tid 0: start offset, tid 1: end offset
        const float* lw = (tid == 0) ? (sw + s * DBINS) : (ew + s * DBINS);
        const float* sl = o + tid * DBINS;
        float m = sl[0];
        for (int jj = 1; jj < DBINS; ++jj) m = fmaxf(m, sl[jj]);
        float sum = 0.f, dot = 0.f;
        for (int jj = 0; jj < DBINS; ++jj) {
            float e = __expf(sl[jj] - m);
            sum += e;
            dot = fmaf(e, lw[jj], dot);
        }
        float off = dot / sum;
        float base = (tid == 0) ? st : en;
        out[a * 2 + tid] = fminf(fmaxf(base + off, 0.f), al);
    }
    if (tid == 42) out[2 * NANCH + a] = o[42];                           // conf
    if (tid >= 43 && tid < FOUT) out[3 * NANCH + a * 4 + (tid - 43)] = o[tid]; // cls
}

extern "C" void kernel_launch(void* const* d_in, const int* in_sizes, int n_in,
                              void* d_out, int out_size, void* d_ws, size_t ws_size,
                              hipStream_t stream) {
    const float* emb   = (const float*)d_in[0];
    const float* tpin  = (const float*)d_in[1];
    const float* npred = (const float*)d_in[2];
    const float* alp   = (const float*)d_in[3];
    const float* anch  = (const float*)d_in[4];
    const float* skern = (const float*)d_in[5];
    const float* fWih  = (const float*)d_in[6];
    const float* fWhh  = (const float*)d_in[7];
    const float* fbih  = (const float*)d_in[8];
    const float* fbhh  = (const float*)d_in[9];
    const float* aWih  = (const float*)d_in[10];
    const float* aWhh  = (const float*)d_in[11];
    const float* abih  = (const float*)d_in[12];
    const float* abhh  = (const float*)d_in[13];
    const float* sw    = (const float*)d_in[14];
    const float* ew    = (const float*)d_in[15];
    const float* W1    = (const float*)d_in[16];
    const float* b1    = (const float*)d_in[17];
    const float* W2    = (const float*)d_in[18];
    const float* b2    = (const float*)d_in[19];
    const float* W3    = (const float*)d_in[20];
    const float* b3    = (const float*)d_in[21];

    float* ws = (float*)d_ws;
    float* xW       = ws;                      // 6*512*384 = 1179648
    float* abn_res  = ws + 1179648;            // 192 (pad 256)
    float* feat     = ws + 1179904;            // 192*256 = 49152
    int*   members  = (int*)(ws + 1229056);    // 192*512 ints = 98304
    int*   lens     = (int*)(ws + 1327360);    // 192 ints
    float* outp     = (float*)d_out;

    prep_kernel<<<384, 384, 0, stream>>>(emb, tpin, fWih, fbih, alp, anch, npred, skern,
                                         aWih, aWhh, abih, abhh,
                                         xW, members, lens, abn_res);
    gru_feat_kernel<<<2 * NANCH, 512, 0, stream>>>(xW, fWhh, fbhh, members, lens, anch, feat);
    head_kernel<<<NANCH, 256, 0, stream>>>(feat, abn_res, anch, alp,
                                           W1, b1, W2, b2, W3, b3, sw, ew, outp);
}